// Round 1
// baseline (2549.378 us; speedup 1.0000x reference)
//
#include <hip/hip_runtime.h>
#include <hip/hip_bf16.h>
#include <hip/hip_fp16.h>

#define L_DIM 2048
#define D_DIM 1024
#define NBATCH 8

typedef __attribute__((ext_vector_type(8))) _Float16 f16x8;
typedef __attribute__((ext_vector_type(4))) _Float16 f16x4;
typedef __attribute__((ext_vector_type(4))) float f32x4;

// Stage panel chunk [32][128] -> sA[32][136], stream chunk [64][128] -> sB[64][136] (fp32 -> fp16)
__device__ __forceinline__ void stage_qk(const float* __restrict__ fp,
                                         const float* __restrict__ fs,
                                         int d0, int n0, int tid,
                                         _Float16* sA, _Float16* sB) {
#pragma unroll
  for (int it = 0; it < 2; ++it) {
    int f4 = it * 512 + tid;
    int row = f4 >> 5, c4 = f4 & 31;
    float4 v = *reinterpret_cast<const float4*>(fp + (size_t)row * D_DIM + d0 + c4 * 4);
    f16x4 h = {(_Float16)v.x, (_Float16)v.y, (_Float16)v.z, (_Float16)v.w};
    *reinterpret_cast<f16x4*>(&sA[row * 136 + c4 * 4]) = h;
  }
#pragma unroll
  for (int it = 0; it < 4; ++it) {
    int f4 = it * 512 + tid;
    int row = f4 >> 5, c4 = f4 & 31;
    float4 v = *reinterpret_cast<const float4*>(fs + (size_t)(n0 + row) * D_DIM + d0 + c4 * 4);
    f16x4 h = {(_Float16)v.x, (_Float16)v.y, (_Float16)v.z, (_Float16)v.w};
    *reinterpret_cast<f16x4*>(&sB[row * 136 + c4 * 4]) = h;
  }
}

// Kernel 1: per-row (max, 1/sumexp) of S = Fp @ Fs^T. Block = 32 rows of Fp.
__global__ __launch_bounds__(512, 4)
void ma_stats_kernel(const float* __restrict__ Fp, const float* __restrict__ Fs,
                     float* __restrict__ stats) {
  __shared__ _Float16 sA[32 * 136];
  __shared__ _Float16 sB[64 * 136];
  __shared__ float sRed[32][4][2];

  const int tid = threadIdx.x;
  const int lane = tid & 63;
  const int w = tid >> 6;
  const int rh = w >> 2, cq = w & 3;
  const int b = blockIdx.y;
  const int m0 = blockIdx.x * 32;

  const float* fp = Fp + (size_t)b * L_DIM * D_DIM + (size_t)m0 * D_DIM;
  const float* fs = Fs + (size_t)b * L_DIM * D_DIM;

  const int frow = lane & 15;
  const int kgrp = (lane >> 4) * 8;

  float mx[4], sm[4];
#pragma unroll
  for (int r = 0; r < 4; ++r) { mx[r] = -1e30f; sm[r] = 0.f; }

  for (int nt = 0; nt < 32; ++nt) {
    const int n0 = nt * 64;
    f32x4 sacc = {0.f, 0.f, 0.f, 0.f};
    for (int kc = 0; kc < 8; ++kc) {
      const int d0 = kc * 128;
      stage_qk(fp, fs, d0, n0, tid, sA, sB);
      __syncthreads();
#pragma unroll
      for (int ks = 0; ks < 4; ++ks) {
        f16x8 a = *reinterpret_cast<const f16x8*>(&sA[(16 * rh + frow) * 136 + ks * 32 + kgrp]);
        f16x8 bb = *reinterpret_cast<const f16x8*>(&sB[(16 * cq + frow) * 136 + ks * 32 + kgrp]);
        sacc = __builtin_amdgcn_mfma_f32_16x16x32_f16(a, bb, sacc, 0, 0, 0);
      }
      __syncthreads();
    }
#pragma unroll
    for (int r = 0; r < 4; ++r) {
      float v = sacc[r];
      float nm = fmaxf(mx[r], v);
      sm[r] = sm[r] * __expf(mx[r] - nm) + __expf(v - nm);
      mx[r] = nm;
    }
  }
  // reduce (max,sum) across the 16 lanes that share a row within the wave
#pragma unroll
  for (int r = 0; r < 4; ++r) {
    float m = mx[r], s = sm[r];
#pragma unroll
    for (int off = 1; off < 16; off <<= 1) {
      float om = __shfl_xor(m, off, 64);
      float os = __shfl_xor(s, off, 64);
      float nm = fmaxf(m, om);
      s = s * __expf(m - nm) + os * __expf(om - nm);
      m = nm;
    }
    if ((lane & 15) == 0) {
      int row = 16 * rh + (lane >> 4) * 4 + r;
      sRed[row][cq][0] = m;
      sRed[row][cq][1] = s;
    }
  }
  __syncthreads();
  if (tid < 32) {
    float m = sRed[tid][0][0];
#pragma unroll
    for (int i = 1; i < 4; ++i) m = fmaxf(m, sRed[tid][i][0]);
    float l = 0.f;
#pragma unroll
    for (int i = 0; i < 4; ++i) l += sRed[tid][i][1] * __expf(sRed[tid][i][0] - m);
    size_t gr = (size_t)b * L_DIM + m0 + tid;
    stats[2 * gr] = m;
    stats[2 * gr + 1] = 1.0f / l;
  }
}

// Kernel 2/3: Out[panel_row][d] = sum_s P(panel_row, s) * Fs[s][d]
// COL_STATS=false: P = softmax over streamed dim, stats indexed by panel row (attended_1)
// COL_STATS=true : stats indexed by streamed col (attended_2 = P^T @ f1)
template <bool COL_STATS>
__global__ __launch_bounds__(512, 4)
void ma_attn_pv(const float* __restrict__ Fp, const float* __restrict__ Fs,
                const float* __restrict__ stats, float* __restrict__ Out) {
  __shared__ _Float16 sA[32 * 136];
  __shared__ _Float16 sB[64 * 136];
  __shared__ _Float16 sP[32 * 72];
  __shared__ _Float16 sV[128 * 64];  // transposed [d][n], XOR-swizzled
  __shared__ float sStats[COL_STATS ? 4096 : 4];

  const int tid = threadIdx.x;
  const int lane = tid & 63;
  const int w = tid >> 6;
  const int rh = w >> 2, cq = w & 3;
  const int b = blockIdx.y;
  const int m0 = blockIdx.x * 32;

  const float* fp = Fp + (size_t)b * L_DIM * D_DIM + (size_t)m0 * D_DIM;
  const float* fs = Fs + (size_t)b * L_DIM * D_DIM;
  float* outp = Out + (size_t)b * L_DIM * D_DIM;

  const int frow = lane & 15;
  const int kgrp = (lane >> 4) * 8;

  if constexpr (COL_STATS) {
    const float4* src = reinterpret_cast<const float4*>(stats + (size_t)b * L_DIM * 2);
#pragma unroll
    for (int it = 0; it < 2; ++it) {
      int i4 = it * 512 + tid;
      *reinterpret_cast<float4*>(&sStats[i4 * 4]) = src[i4];
    }
  }
  float msr[4], lir[4];
  if constexpr (!COL_STATS) {
    int rb = 16 * rh + (lane >> 4) * 4;
#pragma unroll
    for (int r = 0; r < 4; ++r) {
      size_t gr = (size_t)b * L_DIM + m0 + rb + r;
      msr[r] = stats[2 * gr];
      lir[r] = stats[2 * gr + 1];
    }
  }

  f32x4 oacc[16];
#pragma unroll
  for (int i = 0; i < 16; ++i) oacc[i] = (f32x4){0.f, 0.f, 0.f, 0.f};

  const int dg = tid & 31, ng = tid >> 5;

  for (int nt = 0; nt < 32; ++nt) {
    const int n0 = nt * 64;
    f32x4 sacc = {0.f, 0.f, 0.f, 0.f};
    for (int kc = 0; kc < 8; ++kc) {
      const int d0 = kc * 128;
      stage_qk(fp, fs, d0, n0, tid, sA, sB);
      __syncthreads();
#pragma unroll
      for (int ks = 0; ks < 4; ++ks) {
        f16x8 a = *reinterpret_cast<const f16x8*>(&sA[(16 * rh + frow) * 136 + ks * 32 + kgrp]);
        f16x8 bb = *reinterpret_cast<const f16x8*>(&sB[(16 * cq + frow) * 136 + ks * 32 + kgrp]);
        sacc = __builtin_amdgcn_mfma_f32_16x16x32_f16(a, bb, sacc, 0, 0, 0);
      }
      __syncthreads();
    }
    // P = exp(S - m) / l  -> sP[32][72] fp16
    if constexpr (!COL_STATS) {
#pragma unroll
      for (int r = 0; r < 4; ++r) {
        float p = __expf(sacc[r] - msr[r]) * lir[r];
        sP[(16 * rh + (lane >> 4) * 4 + r) * 72 + 16 * cq + frow] = (_Float16)p;
      }
    } else {
      int mcol = n0 + 16 * cq + frow;
      float2 st = *reinterpret_cast<const float2*>(&sStats[2 * mcol]);
#pragma unroll
      for (int r = 0; r < 4; ++r) {
        float p = __expf(sacc[r] - st.x) * st.y;
        sP[(16 * rh + (lane >> 4) * 4 + r) * 72 + 16 * cq + frow] = (_Float16)p;
      }
    }
    __syncthreads();
    f16x8 pa[2][2];
#pragma unroll
    for (int fr = 0; fr < 2; ++fr)
#pragma unroll
      for (int ks = 0; ks < 2; ++ks)
        pa[fr][ks] = *reinterpret_cast<const f16x8*>(&sP[(16 * fr + frow) * 72 + ks * 32 + kgrp]);

    // PV: stream Fs cols in 8 chunks of 128, staged transposed+swizzled
    for (int dc = 0; dc < 8; ++dc) {
      const int d0 = dc * 128;
      float4 v[4];
#pragma unroll
      for (int i = 0; i < 4; ++i)
        v[i] = *reinterpret_cast<const float4*>(fs + (size_t)(n0 + 4 * ng + i) * D_DIM + d0 + 4 * dg);
#pragma unroll
      for (int j = 0; j < 4; ++j) {
        f16x4 t = {(_Float16)((&v[0].x)[j]), (_Float16)((&v[1].x)[j]),
                   (_Float16)((&v[2].x)[j]), (_Float16)((&v[3].x)[j])};
        int d = 4 * dg + j;
        int byteoff = d * 128 + ((8 * ng) ^ ((dg & 7) << 4));
        *reinterpret_cast<f16x4*>(reinterpret_cast<char*>(sV) + byteoff) = t;
      }
      __syncthreads();
      const int dloc = 16 * w + frow;
      const int swz = ((dloc >> 2) & 7) << 4;
#pragma unroll
      for (int ks = 0; ks < 2; ++ks) {
        int nb = (ks * 32 + kgrp) * 2;
        f16x8 vb = *reinterpret_cast<const f16x8*>(
            reinterpret_cast<const char*>(sV) + dloc * 128 + (nb ^ swz));
#pragma unroll
        for (int fr = 0; fr < 2; ++fr)
          oacc[dc * 2 + fr] =
              __builtin_amdgcn_mfma_f32_16x16x32_f16(pa[fr][ks], vb, oacc[dc * 2 + fr], 0, 0, 0);
      }
      __syncthreads();
    }
  }

  // epilogue: fp32 stores
#pragma unroll
  for (int dc = 0; dc < 8; ++dc)
#pragma unroll
    for (int fr = 0; fr < 2; ++fr) {
      int col = dc * 128 + w * 16 + frow;
      int rb = m0 + 16 * fr + (lane >> 4) * 4;
      f32x4 o = oacc[dc * 2 + fr];
#pragma unroll
      for (int r = 0; r < 4; ++r)
        outp[(size_t)(rb + r) * D_DIM + col] = o[r];
    }
}

extern "C" void kernel_launch(void* const* d_in, const int* in_sizes, int n_in,
                              void* d_out, int out_size, void* d_ws, size_t ws_size,
                              hipStream_t stream) {
  const float* f1 = (const float*)d_in[0];
  const float* f2 = (const float*)d_in[1];
  float* out = (float*)d_out;
  float* stats = (float*)d_ws;  // [B][2048][2] = 128 KB

  dim3 grid(L_DIM / 32, NBATCH);
  dim3 blk(512);

  ma_stats_kernel<<<grid, blk, 0, stream>>>(f1, f2, stats);
  ma_attn_pv<false><<<grid, blk, 0, stream>>>(f1, f2, stats, out);
  ma_attn_pv<true><<<grid, blk, 0, stream>>>(f2, f1, stats,
                                             out + (size_t)NBATCH * L_DIM * D_DIM);
}

// Round 2
// 444.364 us; speedup vs baseline: 5.7371x; 5.7371x over previous
//
#include <hip/hip_runtime.h>
#include <hip/hip_fp16.h>

#define LDIM 2048
#define DDIM 1024
#define NBATCH 8

typedef __attribute__((ext_vector_type(8))) _Float16 f16x8;
typedef __attribute__((ext_vector_type(4))) _Float16 f16x4;
typedef __attribute__((ext_vector_type(4))) float f32x4;
typedef unsigned int u32;

#define MFMA16(a, b, c) __builtin_amdgcn_mfma_f32_16x16x32_f16(a, b, c, 0, 0, 0)

// element half-index inside a [256 rows][32 k] fp16 LDS tile, XOR-swizzled so that
// frag reads (16 rows at same 16B k-slot) and staged writes are <=2-way conflicts.
__device__ __forceinline__ int ldsIdx(int row, int k) {
  return (row << 5) + (k ^ ((row & 3) << 3));
}

__device__ __forceinline__ f16x8 cvt8(float4 x, float4 y) {
  f16x8 h = {(_Float16)x.x, (_Float16)x.y, (_Float16)x.z, (_Float16)x.w,
             (_Float16)y.x, (_Float16)y.y, (_Float16)y.z, (_Float16)y.w};
  return h;
}

// ---------------------------------------------------------------------------
// K1: S = F1 F2^T tile GEMM (256x256x1024). Writes P_unnorm = exp(S - m_block)
// (fp16) and per-(row, n-block) partial stats (m_p, l_p).
// ---------------------------------------------------------------------------
__global__ __launch_bounds__(512, 2)
void k_qk_pstats(const float* __restrict__ F1, const float* __restrict__ F2,
                 _Float16* __restrict__ P, float2* __restrict__ partials) {
  __shared__ _Float16 lds[2][2][8192];
  __shared__ float sRedM[1024];
  __shared__ float sRedS[1024];
  __shared__ float sM[256];

  const int tid = threadIdx.x;
  const int lane = tid & 63;
  const int w = tid >> 6, wm = w >> 2, wn = w & 3;
  const int l15 = lane & 15, g4 = lane >> 4;

  const int nwg = gridDim.x;                     // 512
  const int orig = blockIdx.x;
  const int idx = (orig & 7) * (nwg >> 3) + (orig >> 3);   // XCD swizzle
  const int b = idx >> 6;
  const int mblk = (idx >> 3) & 7, nblk = idx & 7;
  const int m0 = mblk << 8, n0 = nblk << 8;

  const float* f1 = F1 + (size_t)b * LDIM * DDIM;
  const float* f2 = F2 + (size_t)b * LDIM * DDIM;

  const int srow = tid >> 1, sh = (tid & 1) << 4;   // staging: row, k-half (0/16)

  f32x4 acc[8][4];
#pragma unroll
  for (int i = 0; i < 8; ++i)
#pragma unroll
    for (int j = 0; j < 4; ++j) acc[i][j] = (f32x4){0.f, 0.f, 0.f, 0.f};

  const float* pa = f1 + (size_t)(m0 + srow) * DDIM + sh;
  const float* pb = f2 + (size_t)(n0 + srow) * DDIM + sh;

  // prologue: stage tile 0
  {
    float4 a0 = *(const float4*)(pa), a1 = *(const float4*)(pa + 4),
           a2 = *(const float4*)(pa + 8), a3 = *(const float4*)(pa + 12);
    float4 b0 = *(const float4*)(pb), b1 = *(const float4*)(pb + 4),
           b2 = *(const float4*)(pb + 8), b3 = *(const float4*)(pb + 12);
    *(f16x8*)&lds[0][0][ldsIdx(srow, sh)] = cvt8(a0, a1);
    *(f16x8*)&lds[0][0][ldsIdx(srow, sh + 8)] = cvt8(a2, a3);
    *(f16x8*)&lds[0][1][ldsIdx(srow, sh)] = cvt8(b0, b1);
    *(f16x8*)&lds[0][1][ldsIdx(srow, sh + 8)] = cvt8(b2, b3);
  }
  __syncthreads();

  int cur = 0;
  for (int t = 0; t < 32; ++t) {
    float4 a0, a1, a2, a3, b0, b1, b2, b3;
    const bool pf = t < 31;
    if (pf) {
      const float* qa = pa + (t + 1) * 32;
      const float* qb = pb + (t + 1) * 32;
      a0 = *(const float4*)(qa); a1 = *(const float4*)(qa + 4);
      a2 = *(const float4*)(qa + 8); a3 = *(const float4*)(qa + 12);
      b0 = *(const float4*)(qb); b1 = *(const float4*)(qb + 4);
      b2 = *(const float4*)(qb + 8); b3 = *(const float4*)(qb + 12);
    }
    f16x8 af[8], bf[4];
#pragma unroll
    for (int mr = 0; mr < 8; ++mr)
      af[mr] = *(const f16x8*)&lds[cur][0][ldsIdx(wm * 128 + mr * 16 + l15, g4 << 3)];
#pragma unroll
    for (int nr = 0; nr < 4; ++nr)
      bf[nr] = *(const f16x8*)&lds[cur][1][ldsIdx(wn * 64 + nr * 16 + l15, g4 << 3)];
#pragma unroll
    for (int mr = 0; mr < 8; ++mr)
#pragma unroll
      for (int nr = 0; nr < 4; ++nr)
        acc[mr][nr] = MFMA16(af[mr], bf[nr], acc[mr][nr]);
    if (pf) {
      const int nx = cur ^ 1;
      *(f16x8*)&lds[nx][0][ldsIdx(srow, sh)] = cvt8(a0, a1);
      *(f16x8*)&lds[nx][0][ldsIdx(srow, sh + 8)] = cvt8(a2, a3);
      *(f16x8*)&lds[nx][1][ldsIdx(srow, sh)] = cvt8(b0, b1);
      *(f16x8*)&lds[nx][1][ldsIdx(srow, sh + 8)] = cvt8(b2, b3);
    }
    __syncthreads();
    cur ^= 1;
  }

  // ---- epilogue: block-partial softmax stats + P_unnorm store ----
  // row-max over this block's 256 n-cols
#pragma unroll
  for (int mr = 0; mr < 8; ++mr)
#pragma unroll
    for (int r = 0; r < 4; ++r) {
      float v = fmaxf(fmaxf(acc[mr][0][r], acc[mr][1][r]),
                      fmaxf(acc[mr][2][r], acc[mr][3][r]));
#pragma unroll
      for (int off = 1; off < 16; off <<= 1) v = fmaxf(v, __shfl_xor(v, off, 64));
      if (l15 == 0) sRedM[(wm * 128 + mr * 16 + g4 * 4 + r) * 4 + wn] = v;
    }
  __syncthreads();
  if (tid < 256) {
    float m = fmaxf(fmaxf(sRedM[tid * 4], sRedM[tid * 4 + 1]),
                    fmaxf(sRedM[tid * 4 + 2], sRedM[tid * 4 + 3]));
    sM[tid] = m;
  }
  __syncthreads();

  _Float16* pOut = P + ((size_t)b << 22);
#pragma unroll
  for (int mr = 0; mr < 8; ++mr)
#pragma unroll
    for (int r = 0; r < 4; ++r) {
      const int rowl = wm * 128 + mr * 16 + g4 * 4 + r;
      const float m = sM[rowl];
      float s = 0.f;
#pragma unroll
      for (int nr = 0; nr < 4; ++nr) {
        float p = __expf(acc[mr][nr][r] - m);
        s += p;
        pOut[(size_t)(m0 + rowl) * LDIM + n0 + wn * 64 + nr * 16 + l15] = (_Float16)p;
      }
#pragma unroll
      for (int off = 1; off < 16; off <<= 1) s += __shfl_xor(s, off, 64);
      if (l15 == 0) sRedS[rowl * 4 + wn] = s;
    }
  __syncthreads();
  if (tid < 256) {
    float l = sRedS[tid * 4] + sRedS[tid * 4 + 1] + sRedS[tid * 4 + 2] + sRedS[tid * 4 + 3];
    partials[(((size_t)b * 8 + nblk) << 11) + m0 + tid] = make_float2(sM[tid], l);
  }
}

// ---------------------------------------------------------------------------
// merge partial stats -> per-(row, n-block) rescale factors e^(m_p - M) / L
// ---------------------------------------------------------------------------
__global__ void k_merge(const float2* __restrict__ partials, float* __restrict__ factors) {
  const int t = blockIdx.x * 256 + threadIdx.x;
  if (t >= NBATCH * LDIM) return;
  const int b = t >> 11, row = t & 2047;
  float2 p[8];
  float M = -1e30f;
#pragma unroll
  for (int i = 0; i < 8; ++i) {
    p[i] = partials[(((size_t)b * 8 + i) << 11) + row];
    M = fmaxf(M, p[i].x);
  }
  float L = 0.f;
#pragma unroll
  for (int i = 0; i < 8; ++i) L += p[i].y * __expf(p[i].x - M);
  const float inv = 1.0f / L;
#pragma unroll
  for (int i = 0; i < 8; ++i)
    factors[(((size_t)b * 8 + i) << 11) + row] = __expf(p[i].x - M) * inv;
}

// ---------------------------------------------------------------------------
// rescale P in place: P[b][m][n] *= factors[b][n>>8][m]
// ---------------------------------------------------------------------------
__global__ void k_rescale(_Float16* __restrict__ P, const float* __restrict__ factors) {
  const int total = (NBATCH * LDIM * LDIM) / 8;   // vec8 count
  for (int i = blockIdx.x * 256 + threadIdx.x; i < total; i += gridDim.x * 256) {
    const int flat = i * 8;
    const int b = flat >> 22;
    const int r = flat & ((1 << 22) - 1);
    const int m = r >> 11;
    const int n = r & 2047;
    const int nb = n >> 8;
    const float f = factors[(((size_t)b * 8 + nb) << 11) + m];
    const _Float16 hf = (_Float16)f;
    f16x8 h = *(f16x8*)(P + (size_t)flat);
#pragma unroll
    for (int j = 0; j < 8; ++j) h[j] = h[j] * hf;
    *(f16x8*)(P + (size_t)flat) = h;
  }
}

// ---------------------------------------------------------------------------
// K3: attended_1 = P @ F2   (M=2048 rows of P, N=1024 d-cols, K=2048)
// A-tile: P fp16 direct. B-tile: F2[k=n][d] transpose-staged + fp32->fp16.
// ---------------------------------------------------------------------------
__global__ __launch_bounds__(512, 2)
void k_att1(const _Float16* __restrict__ P, const float* __restrict__ F2,
            float* __restrict__ Out) {
  __shared__ _Float16 lds[2][2][8192];

  const int tid = threadIdx.x;
  const int lane = tid & 63;
  const int w = tid >> 6, wm = w >> 2, wn = w & 3;
  const int l15 = lane & 15, g4 = lane >> 4;

  const int nwg = gridDim.x;                      // 256
  const int orig = blockIdx.x;
  const int idx = (orig & 7) * (nwg >> 3) + (orig >> 3);
  const int b = idx >> 5;
  const int mblk = (idx >> 2) & 7, dblk = idx & 3;
  const int m0 = mblk << 8, d0 = dblk << 8;

  const _Float16* p = P + ((size_t)b << 22);
  const float* f2 = F2 + (size_t)b * LDIM * DDIM;
  float* outp = Out + (size_t)b * LDIM * DDIM;

  const int srow = tid >> 1, sh = (tid & 1) << 4;   // A staging
  const int bdg = tid >> 3, bng = tid & 7;          // B staging (write-conflict-free)

  f32x4 acc[8][4];
#pragma unroll
  for (int i = 0; i < 8; ++i)
#pragma unroll
    for (int j = 0; j < 4; ++j) acc[i][j] = (f32x4){0.f, 0.f, 0.f, 0.f};

  // prologue
  {
    const _Float16* qa = p + (size_t)(m0 + srow) * LDIM + sh;
    uint4 va0 = *(const uint4*)(qa), va1 = *(const uint4*)(qa + 8);
    *(uint4*)&lds[0][0][ldsIdx(srow, sh)] = va0;
    *(uint4*)&lds[0][0][ldsIdx(srow, sh + 8)] = va1;
    float4 vb[4];
#pragma unroll
    for (int i = 0; i < 4; ++i)
      vb[i] = *(const float4*)(f2 + (size_t)(bng * 4 + i) * DDIM + d0 + bdg * 4);
#pragma unroll
    for (int j = 0; j < 4; ++j) {
      f16x4 hv = {(_Float16)((&vb[0].x)[j]), (_Float16)((&vb[1].x)[j]),
                  (_Float16)((&vb[2].x)[j]), (_Float16)((&vb[3].x)[j])};
      *(f16x4*)&lds[0][1][(((bdg << 2) + j) << 5) + ((bng << 2) ^ (j << 3))] = hv;
    }
  }
  __syncthreads();

  int cur = 0;
  for (int t = 0; t < 64; ++t) {
    uint4 va0, va1;
    float4 vb[4];
    const bool pf = t < 63;
    if (pf) {
      const int kb = (t + 1) * 32;
      const _Float16* qa = p + (size_t)(m0 + srow) * LDIM + kb + sh;
      va0 = *(const uint4*)(qa);
      va1 = *(const uint4*)(qa + 8);
#pragma unroll
      for (int i = 0; i < 4; ++i)
        vb[i] = *(const float4*)(f2 + (size_t)(kb + bng * 4 + i) * DDIM + d0 + bdg * 4);
    }
    f16x8 af[8], bf[4];
#pragma unroll
    for (int mr = 0; mr < 8; ++mr)
      af[mr] = *(const f16x8*)&lds[cur][0][ldsIdx(wm * 128 + mr * 16 + l15, g4 << 3)];
#pragma unroll
    for (int nr = 0; nr < 4; ++nr)
      bf[nr] = *(const f16x8*)&lds[cur][1][ldsIdx(wn * 64 + nr * 16 + l15, g4 << 3)];
#pragma unroll
    for (int mr = 0; mr < 8; ++mr)
#pragma unroll
      for (int nr = 0; nr < 4; ++nr)
        acc[mr][nr] = MFMA16(af[mr], bf[nr], acc[mr][nr]);
    if (pf) {
      const int nx = cur ^ 1;
      *(uint4*)&lds[nx][0][ldsIdx(srow, sh)] = va0;
      *(uint4*)&lds[nx][0][ldsIdx(srow, sh + 8)] = va1;
#pragma unroll
      for (int j = 0; j < 4; ++j) {
        f16x4 hv = {(_Float16)((&vb[0].x)[j]), (_Float16)((&vb[1].x)[j]),
                    (_Float16)((&vb[2].x)[j]), (_Float16)((&vb[3].x)[j])};
        *(f16x4*)&lds[nx][1][(((bdg << 2) + j) << 5) + ((bng << 2) ^ (j << 3))] = hv;
      }
    }
    __syncthreads();
    cur ^= 1;
  }

#pragma unroll
  for (int mr = 0; mr < 8; ++mr)
#pragma unroll
    for (int nr = 0; nr < 4; ++nr)
#pragma unroll
      for (int r = 0; r < 4; ++r)
        outp[(size_t)(m0 + wm * 128 + mr * 16 + g4 * 4 + r) * DDIM +
             d0 + wn * 64 + nr * 16 + l15] = acc[mr][nr][r];
}

// ---------------------------------------------------------------------------
// K4: attended_2 = P^T @ F1   (M=2048 n-rows, N=1024 d-cols, K=2048 m)
// A-tile: P transpose-staged (fp16). B-tile: F1 transpose-staged + convert.
// ---------------------------------------------------------------------------
__global__ __launch_bounds__(512, 2)
void k_att2(const _Float16* __restrict__ P, const float* __restrict__ F1,
            float* __restrict__ Out) {
  __shared__ _Float16 lds[2][2][8192];

  const int tid = threadIdx.x;
  const int lane = tid & 63;
  const int w = tid >> 6, wm = w >> 2, wn = w & 3;
  const int l15 = lane & 15, g4 = lane >> 4;

  const int nwg = gridDim.x;                      // 256
  const int orig = blockIdx.x;
  const int idx = (orig & 7) * (nwg >> 3) + (orig >> 3);
  const int b = idx >> 5;
  const int nblk = (idx >> 2) & 7, dblk = idx & 3;
  const int n0 = nblk << 8, d0 = dblk << 8;

  const _Float16* p = P + ((size_t)b << 22);
  const float* f1 = F1 + (size_t)b * LDIM * DDIM;
  float* outp = Out + (size_t)b * LDIM * DDIM;

  const int amg = tid & 15, ang = tid >> 4;       // A: m-pair, n8-group (write-clean)
  const int bdg = tid >> 3, bng = tid & 7;        // B staging

  f32x4 acc[8][4];
#pragma unroll
  for (int i = 0; i < 8; ++i)
#pragma unroll
    for (int j = 0; j < 4; ++j) acc[i][j] = (f32x4){0.f, 0.f, 0.f, 0.f};

  auto writeA = [&](int buf, uint4 q0, uint4 q1) {
    const u32 q0a[4] = {q0.x, q0.y, q0.z, q0.w};
    const u32 q1a[4] = {q1.x, q1.y, q1.z, q1.w};
#pragma unroll
    for (int j = 0; j < 8; ++j) {
      const u32 lo = (q0a[j >> 1] >> ((j & 1) * 16)) & 0xffffu;
      const u32 hi = (j & 1) ? (q1a[j >> 1] & 0xffff0000u) : (q1a[j >> 1] << 16);
      const int row = ang * 8 + j;
      *(u32*)&lds[buf][0][(row << 5) + ((amg * 2) ^ ((j & 3) << 3))] = lo | hi;
    }
  };
  auto writeB = [&](int buf, const float4* vb) {
#pragma unroll
    for (int j = 0; j < 4; ++j) {
      f16x4 hv = {(_Float16)((&vb[0].x)[j]), (_Float16)((&vb[1].x)[j]),
                  (_Float16)((&vb[2].x)[j]), (_Float16)((&vb[3].x)[j])};
      *(f16x4*)&lds[buf][1][(((bdg << 2) + j) << 5) + ((bng << 2) ^ (j << 3))] = hv;
    }
  };

  // prologue
  {
    uint4 q0 = *(const uint4*)(p + (size_t)(amg * 2) * LDIM + n0 + ang * 8);
    uint4 q1 = *(const uint4*)(p + (size_t)(amg * 2 + 1) * LDIM + n0 + ang * 8);
    float4 vb[4];
#pragma unroll
    for (int i = 0; i < 4; ++i)
      vb[i] = *(const float4*)(f1 + (size_t)(bng * 4 + i) * DDIM + d0 + bdg * 4);
    writeA(0, q0, q1);
    writeB(0, vb);
  }
  __syncthreads();

  int cur = 0;
  for (int t = 0; t < 64; ++t) {
    uint4 q0, q1;
    float4 vb[4];
    const bool pf = t < 63;
    if (pf) {
      const int kb = (t + 1) * 32;
      q0 = *(const uint4*)(p + (size_t)(kb + amg * 2) * LDIM + n0 + ang * 8);
      q1 = *(const uint4*)(p + (size_t)(kb + amg * 2 + 1) * LDIM + n0 + ang * 8);
#pragma unroll
      for (int i = 0; i < 4; ++i)
        vb[i] = *(const float4*)(f1 + (size_t)(kb + bng * 4 + i) * DDIM + d0 + bdg * 4);
    }
    f16x8 af[8], bf[4];
#pragma unroll
    for (int mr = 0; mr < 8; ++mr)
      af[mr] = *(const f16x8*)&lds[cur][0][ldsIdx(wm * 128 + mr * 16 + l15, g4 << 3)];
#pragma unroll
    for (int nr = 0; nr < 4; ++nr)
      bf[nr] = *(const f16x8*)&lds[cur][1][ldsIdx(wn * 64 + nr * 16 + l15, g4 << 3)];
#pragma unroll
    for (int mr = 0; mr < 8; ++mr)
#pragma unroll
      for (int nr = 0; nr < 4; ++nr)
        acc[mr][nr] = MFMA16(af[mr], bf[nr], acc[mr][nr]);
    if (pf) {
      writeA(cur ^ 1, q0, q1);
      writeB(cur ^ 1, vb);
    }
    __syncthreads();
    cur ^= 1;
  }

#pragma unroll
  for (int mr = 0; mr < 8; ++mr)
#pragma unroll
    for (int nr = 0; nr < 4; ++nr)
#pragma unroll
      for (int r = 0; r < 4; ++r)
        outp[(size_t)(n0 + wm * 128 + mr * 16 + g4 * 4 + r) * DDIM +
             d0 + wn * 64 + nr * 16 + l15] = acc[mr][nr][r];
}

// ---------------------------------------------------------------------------
extern "C" void kernel_launch(void* const* d_in, const int* in_sizes, int n_in,
                              void* d_out, int out_size, void* d_ws, size_t ws_size,
                              hipStream_t stream) {
  const float* f1 = (const float*)d_in[0];
  const float* f2 = (const float*)d_in[1];
  float* out1 = (float*)d_out;
  float* out2 = out1 + (size_t)NBATCH * LDIM * DDIM;

  _Float16* P = (_Float16*)d_ws;                                   // 64 MB
  float2* partials = (float2*)((char*)d_ws + 67108864);            // 1 MB
  float* factors = (float*)((char*)d_ws + 67108864 + 1048576);     // 512 KB

  k_qk_pstats<<<dim3(512), dim3(512), 0, stream>>>(f1, f2, P, partials);
  k_merge<<<dim3(64), dim3(256), 0, stream>>>(partials, factors);
  k_rescale<<<dim3(2048), dim3(256), 0, stream>>>(P, factors);
  k_att1<<<dim3(256), dim3(512), 0, stream>>>(P, f2, out1);
  k_att2<<<dim3(256), dim3(512), 0, stream>>>(P, f1, out2);
}

// Round 3
// 283.713 us; speedup vs baseline: 8.9858x; 1.5662x over previous
//
#include <hip/hip_runtime.h>
#include <hip/hip_fp16.h>

#define LDIM 2048
#define DDIM 1024
#define NB 8

typedef __attribute__((ext_vector_type(8))) _Float16 f16x8;
typedef __attribute__((ext_vector_type(4))) float f32x4;
typedef unsigned int u32;

#define MFMA16(a, b, c) __builtin_amdgcn_mfma_f32_16x16x32_f16(a, b, c, 0, 0, 0)

typedef const __attribute__((address_space(1))) u32* gas_t;
typedef __attribute__((address_space(3))) u32* las_t;

__device__ __forceinline__ void gl16(const _Float16* g, _Float16* l) {
  __builtin_amdgcn_global_load_lds((gas_t)g, (las_t)l, 16, 0, 0);
}

// ---------------------------------------------------------------------------
// GEMM core: C_tile(128x128) += A(128 rows, K-major, LDA halves) x B^T.
// Single-buffered LDS, BK=64, gload_lds w=16 with pre-swizzled source.
// acc[mr][nr]: wave (wm=w>>1, wn=w&1) owns 64x64; m = wm*64+mr*16+g4*4+r,
// n = wn*64+nr*16+l15.
// ---------------------------------------------------------------------------
template <int KT, int LDA>
__device__ __forceinline__ void gemm_core(const _Float16* __restrict__ Arow0,
                                          const _Float16* __restrict__ Brow0,
                                          _Float16* sA, _Float16* sB,
                                          f32x4 acc[4][4], int tid) {
  const int w = tid >> 6, lane = tid & 63;
  const int wm = w >> 1, wn = w & 1;
  const int l15 = lane & 15, g4 = lane >> 4;

  const int rb = tid >> 3;                       // staging row 0..31 (per issue +32)
  const int csw = (tid & 7) ^ (rb & 7);          // pre-swizzled source chunk
  const _Float16* ga = Arow0 + (size_t)rb * LDA + csw * 8;
  const _Float16* gb = Brow0 + (size_t)rb * LDA + csw * 8;
  _Float16* da = sA + (w << 9);
  _Float16* db = sB + (w << 9);

  for (int kt = 0; kt < KT; ++kt) {
    const size_t ko = (size_t)kt * 64;
#pragma unroll
    for (int is = 0; is < 4; ++is) {
      gl16(ga + (size_t)(is * 32) * LDA + ko, da + is * 2048);
      gl16(gb + (size_t)(is * 32) * LDA + ko, db + is * 2048);
    }
    __syncthreads();
#pragma unroll
    for (int ks = 0; ks < 2; ++ks) {
      const int cs2 = (((ks << 2) + g4) ^ (l15 & 7)) << 3;
      f16x8 af[4], bf[4];
#pragma unroll
      for (int mr = 0; mr < 4; ++mr)
        af[mr] = *(const f16x8*)&sA[(wm * 64 + mr * 16 + l15) * 64 + cs2];
#pragma unroll
      for (int nr = 0; nr < 4; ++nr)
        bf[nr] = *(const f16x8*)&sB[(wn * 64 + nr * 16 + l15) * 64 + cs2];
#pragma unroll
      for (int mr = 0; mr < 4; ++mr)
#pragma unroll
        for (int nr = 0; nr < 4; ++nr)
          acc[mr][nr] = MFMA16(af[mr], bf[nr], acc[mr][nr]);
    }
    __syncthreads();
  }
}

// ---------------------------------------------------------------------------
// k_prep: F (fp32 [R=2048][C=1024]) -> H (fp16 [R][C]) + HT (fp16 [C][R]).
// 64x64 tiles via LDS transpose. blockIdx.x: [input(2) | b(8) | rt(32) | ct(16)]
// ---------------------------------------------------------------------------
__global__ __launch_bounds__(256)
void k_prep(const float* __restrict__ F1, const float* __restrict__ F2,
            _Float16* __restrict__ H1, _Float16* __restrict__ H2,
            _Float16* __restrict__ H1T, _Float16* __restrict__ H2T) {
  __shared__ _Float16 sT[64][72];
  const int bid = blockIdx.x;
  const int inp = bid >> 12;
  const int rem = bid & 4095;
  const int b = rem >> 9, rt = (rem >> 4) & 31, ct = rem & 15;
  const int r0 = rt * 64, c0 = ct * 64;

  const float* F = (inp ? F2 : F1) + (size_t)b * LDIM * DDIM;
  _Float16* H = (inp ? H2 : H1) + (size_t)b * LDIM * DDIM;
  _Float16* HT = (inp ? H2T : H1T) + (size_t)b * DDIM * LDIM;

  const int t = threadIdx.x;
  const int row = t >> 2, seg = (t & 3) * 16;
  {
    const float* src = F + (size_t)(r0 + row) * DDIM + c0 + seg;
    float4 v0 = *(const float4*)(src), v1 = *(const float4*)(src + 4);
    float4 v2 = *(const float4*)(src + 8), v3 = *(const float4*)(src + 12);
    _Float16 h[16];
#pragma unroll
    for (int j = 0; j < 4; ++j) {
      h[j] = (_Float16)((&v0.x)[j]); h[4 + j] = (_Float16)((&v1.x)[j]);
      h[8 + j] = (_Float16)((&v2.x)[j]); h[12 + j] = (_Float16)((&v3.x)[j]);
    }
    _Float16* dst = H + (size_t)(r0 + row) * DDIM + c0 + seg;
#pragma unroll
    for (int j = 0; j < 16; ++j) dst[j] = h[j];
#pragma unroll
    for (int j = 0; j < 16; ++j) sT[seg + j][row] = h[j];
  }
  __syncthreads();
  {
    const int cloc = t >> 2, rseg = (t & 3) * 16;
    _Float16* dst = HT + (size_t)(c0 + cloc) * LDIM + r0 + rseg;
    *(uint4*)dst = *(const uint4*)&sT[cloc][rseg];
    *(uint4*)(dst + 8) = *(const uint4*)&sT[cloc][rseg + 8];
  }
}

// ---------------------------------------------------------------------------
// k_qk: S = H1 H2^T (128x128 tiles, K=1024). Epilogue: per-row partial max/sum
// over the tile's 128 cols; store P_unnorm fp16 + partials.
// ---------------------------------------------------------------------------
__global__ __launch_bounds__(256, 2)
void k_qk(const _Float16* __restrict__ H1, const _Float16* __restrict__ H2,
          _Float16* __restrict__ P, float2* __restrict__ partials) {
  __shared__ _Float16 sA[8192];
  __shared__ _Float16 sB[8192];
  __shared__ float sRedM[128][2];
  __shared__ float sRedS[128][2];
  __shared__ float sM[128];

  const int tid = threadIdx.x;
  const int lane = tid & 63;
  const int w = tid >> 6, wm = w >> 1, wn = w & 1;
  const int l15 = lane & 15, g4 = lane >> 4;

  const int nwg = gridDim.x;                          // 2048
  const int orig = blockIdx.x;
  const int idx = (orig & 7) * (nwg >> 3) + (orig >> 3);
  const int b = idx >> 8;
  const int mt = (idx >> 4) & 15, nt = idx & 15;
  const int m0 = mt << 7, n0 = nt << 7;

  f32x4 acc[4][4];
#pragma unroll
  for (int i = 0; i < 4; ++i)
#pragma unroll
    for (int j = 0; j < 4; ++j) acc[i][j] = (f32x4){0.f, 0.f, 0.f, 0.f};

  gemm_core<16, 1024>(H1 + (size_t)b * LDIM * DDIM + (size_t)m0 * DDIM,
                      H2 + (size_t)b * LDIM * DDIM + (size_t)n0 * DDIM,
                      sA, sB, acc, tid);

  // row max (within wave: over nr frags + 16 lanes; across wn via LDS)
#pragma unroll
  for (int mr = 0; mr < 4; ++mr)
#pragma unroll
    for (int r = 0; r < 4; ++r) {
      float v = fmaxf(fmaxf(acc[mr][0][r], acc[mr][1][r]),
                      fmaxf(acc[mr][2][r], acc[mr][3][r]));
#pragma unroll
      for (int off = 1; off < 16; off <<= 1) v = fmaxf(v, __shfl_xor(v, off, 64));
      if (l15 == 0) sRedM[wm * 64 + mr * 16 + g4 * 4 + r][wn] = v;
    }
  __syncthreads();
  if (tid < 128) sM[tid] = fmaxf(sRedM[tid][0], sRedM[tid][1]);
  __syncthreads();

  _Float16* pOut = P + ((size_t)b << 22);
#pragma unroll
  for (int mr = 0; mr < 4; ++mr)
#pragma unroll
    for (int r = 0; r < 4; ++r) {
      const int rloc = wm * 64 + mr * 16 + g4 * 4 + r;
      const float m = sM[rloc];
      float s = 0.f;
#pragma unroll
      for (int nr = 0; nr < 4; ++nr) {
        float p = __expf(acc[mr][nr][r] - m);
        s += p;
        pOut[(size_t)(m0 + rloc) * LDIM + n0 + wn * 64 + nr * 16 + l15] = (_Float16)p;
      }
#pragma unroll
      for (int off = 1; off < 16; off <<= 1) s += __shfl_xor(s, off, 64);
      if (l15 == 0) sRedS[rloc][wn] = s;
    }
  __syncthreads();
  if (tid < 128) {
    const float l = sRedS[tid][0] + sRedS[tid][1];
    partials[((size_t)(b * 16 + nt) << 11) + m0 + tid] = make_float2(sM[tid], l);
  }
}

// ---------------------------------------------------------------------------
__global__ void k_merge(const float2* __restrict__ partials, float* __restrict__ factors) {
  const int t = blockIdx.x * 256 + threadIdx.x;
  if (t >= NB * LDIM) return;
  const int b = t >> 11, row = t & 2047;
  float2 p[16];
  float M = -1e30f;
#pragma unroll
  for (int i = 0; i < 16; ++i) {
    p[i] = partials[((size_t)(b * 16 + i) << 11) + row];
    M = fmaxf(M, p[i].x);
  }
  float L = 0.f;
#pragma unroll
  for (int i = 0; i < 16; ++i) L += p[i].y * __expf(p[i].x - M);
  const float inv = 1.0f / L;
#pragma unroll
  for (int i = 0; i < 16; ++i)
    factors[((size_t)(b * 16 + i) << 11) + row] = __expf(p[i].x - M) * inv;
}

// ---------------------------------------------------------------------------
// k_scale_t: P[m][n] *= f[m][n>>7] in place; also write PT[n][m] (rescaled).
// 64x64 tiles. blockIdx.x: [b(8) | mt(32) | nt(32)]
// ---------------------------------------------------------------------------
__global__ __launch_bounds__(256)
void k_scale_t(_Float16* __restrict__ P, const float* __restrict__ factors,
               _Float16* __restrict__ PT) {
  __shared__ _Float16 sT[64][72];
  const int bid = blockIdx.x;
  const int b = bid >> 10, mt = (bid >> 5) & 31, nt = bid & 31;
  const int m0 = mt * 64, n0 = nt * 64;
  const int nblk = n0 >> 7;

  _Float16* p = P + ((size_t)b << 22);
  _Float16* pt = PT + ((size_t)b << 22);

  const int t = threadIdx.x;
  const int row = t >> 2, seg = (t & 3) * 16;
  {
    const float f = factors[((size_t)(b * 16 + nblk) << 11) + m0 + row];
    const _Float16 hf = (_Float16)f;
    _Float16* src = p + (size_t)(m0 + row) * LDIM + n0 + seg;
    f16x8 h0 = *(const f16x8*)src, h1 = *(const f16x8*)(src + 8);
#pragma unroll
    for (int j = 0; j < 8; ++j) { h0[j] *= hf; h1[j] *= hf; }
    *(f16x8*)src = h0;
    *(f16x8*)(src + 8) = h1;
#pragma unroll
    for (int j = 0; j < 8; ++j) { sT[seg + j][row] = h0[j]; sT[seg + 8 + j][row] = h1[j]; }
  }
  __syncthreads();
  {
    const int nloc = t >> 2, mseg = (t & 3) * 16;
    _Float16* dst = pt + (size_t)(n0 + nloc) * LDIM + m0 + mseg;
    *(uint4*)dst = *(const uint4*)&sT[nloc][mseg];
    *(uint4*)(dst + 8) = *(const uint4*)&sT[nloc][mseg + 8];
  }
}

// ---------------------------------------------------------------------------
// k_gemm: C[2048][1024] = A(2048 rows, K=2048) x B(1024 rows, K=2048)^T, fp32 out.
// A = P (or PT), B = H2T (or H1T). 128x128 tiles.
// ---------------------------------------------------------------------------
__global__ __launch_bounds__(256, 2)
void k_gemm(const _Float16* __restrict__ A, const _Float16* __restrict__ B,
            float* __restrict__ C) {
  __shared__ _Float16 sA[8192];
  __shared__ _Float16 sB[8192];

  const int tid = threadIdx.x;
  const int lane = tid & 63;
  const int w = tid >> 6, wm = w >> 1, wn = w & 1;
  const int l15 = lane & 15, g4 = lane >> 4;

  const int nwg = gridDim.x;                          // 1024
  const int orig = blockIdx.x;
  const int idx = (orig & 7) * (nwg >> 3) + (orig >> 3);
  const int b = idx >> 7;
  const int mt = (idx >> 3) & 15, nt = idx & 7;
  const int m0 = mt << 7, d0 = nt << 7;

  f32x4 acc[4][4];
#pragma unroll
  for (int i = 0; i < 4; ++i)
#pragma unroll
    for (int j = 0; j < 4; ++j) acc[i][j] = (f32x4){0.f, 0.f, 0.f, 0.f};

  gemm_core<32, 2048>(A + ((size_t)b << 22) + (size_t)m0 * LDIM,
                      B + ((size_t)b << 21) + (size_t)d0 * LDIM,
                      sA, sB, acc, tid);

  float* outp = C + (size_t)b * LDIM * DDIM;
#pragma unroll
  for (int mr = 0; mr < 4; ++mr)
#pragma unroll
    for (int nr = 0; nr < 4; ++nr)
#pragma unroll
      for (int r = 0; r < 4; ++r)
        outp[(size_t)(m0 + wm * 64 + mr * 16 + g4 * 4 + r) * DDIM +
             d0 + wn * 64 + nr * 16 + l15] = acc[mr][nr][r];
}

// ---------------------------------------------------------------------------
extern "C" void kernel_launch(void* const* d_in, const int* in_sizes, int n_in,
                              void* d_out, int out_size, void* d_ws, size_t ws_size,
                              hipStream_t stream) {
  const float* f1 = (const float*)d_in[0];
  const float* f2 = (const float*)d_in[1];
  float* out1 = (float*)d_out;
  float* out2 = out1 + (size_t)NB * LDIM * DDIM;

  char* ws = (char*)d_ws;
  _Float16* H1T = (_Float16*)(ws);                         // 32 MB
  _Float16* H2T = (_Float16*)(ws + 33554432ull);           // 32 MB
  _Float16* P   = (_Float16*)(ws + 67108864ull);           // 64 MB
  _Float16* PT  = (_Float16*)(ws + 134217728ull);          // 64 MB (overlaps H1,H2)
  _Float16* H1  = (_Float16*)(ws + 134217728ull);          // 32 MB (dead after k_qk)
  _Float16* H2  = (_Float16*)(ws + 167772160ull);          // 32 MB (dead after k_qk)
  float2* partials = (float2*)(ws + 201326592ull);         // 2 MB
  float* factors   = (float*)(ws + 203423744ull);          // 1 MB

  k_prep<<<dim3(8192), dim3(256), 0, stream>>>(f1, f2, H1, H2, H1T, H2T);
  k_qk<<<dim3(2048), dim3(256), 0, stream>>>(H1, H2, P, partials);
  k_merge<<<dim3(64), dim3(256), 0, stream>>>(partials, factors);
  k_scale_t<<<dim3(8192), dim3(256), 0, stream>>>(P, factors, PT);
  k_gemm<<<dim3(1024), dim3(256), 0, stream>>>(P, H2T, out1);
  k_gemm<<<dim3(1024), dim3(256), 0, stream>>>(PT, H1T, out2);
}